// Round 1
// baseline (199.713 us; speedup 1.0000x reference)
//
#include <hip/hip_runtime.h>
#include <math.h>

#define B 4
#define NBC 128
#define HID 64
#define HC 64
#define WC 64
#define P_TOTAL (HC*WC)
#define HOUT 256
#define WOUT 256
#define PT 16   // coarse points per block in main kernel

__device__ __forceinline__ float gelu_exact(float x) {
    return 0.5f * x * (1.0f + erff(x * 0.70710678118654752f));
}

// ---------------------------------------------------------------------------
// Kernel A: per-(b,n) boundary encoder:  bf = gelu(gelu(bi@e1w+e1b)@e2w+e2b)
// then fold bfg = bf @ g1w_f + g1b   -> bfg[b*NBC+n][HID]
// One block of 64 threads per (b,n).
// ---------------------------------------------------------------------------
__global__ void bg_encode(const float* __restrict__ bi,
                          const float* __restrict__ e1w, const float* __restrict__ e1b,
                          const float* __restrict__ e2w, const float* __restrict__ e2b,
                          const float* __restrict__ g1w, const float* __restrict__ g1b,
                          float* __restrict__ bfg) {
    int bn = blockIdx.x;          // 0..B*NBC-1
    int h  = threadIdx.x;         // 0..63
    __shared__ float t1[HID];
    __shared__ float t2[HID];
    float x = bi[bn*3+0], y = bi[bn*3+1], z = bi[bn*3+2];
    float a = x*e1w[0*HID+h] + y*e1w[1*HID+h] + z*e1w[2*HID+h] + e1b[h];
    t1[h] = gelu_exact(a);
    __syncthreads();
    float s = e2b[h];
    #pragma unroll
    for (int k = 0; k < HID; ++k) s += t1[k]*e2w[k*HID+h];
    t2[h] = gelu_exact(s);
    __syncthreads();
    float o = g1b[h];
    #pragma unroll
    for (int k = 0; k < HID; ++k) o += t2[k]*g1w[k*HID+h];   // g1w_f rows 0..63
    bfg[bn*HID+h] = o;
}

// ---------------------------------------------------------------------------
// Kernel B: main contraction over boundary points.
// Block: 256 threads = 16 p_local x 16 n_lanes. Grid: (P_TOTAL/PT, B).
// Each thread: 8 n-iterations, full 64-dim h1 -> 32-dim h2 -> raw, weighted acc.
// ---------------------------------------------------------------------------
__global__ __launch_bounds__(256) void bg_main(
    const float* __restrict__ bi,
    const float* __restrict__ g1w,     // rows 64,65 = g1w_c ; row 66 = g1w_d
    const float* __restrict__ g2w,     // [64][32]
    const float* __restrict__ g2b,     // [32]
    const float* __restrict__ g3w,     // [32]
    const float* __restrict__ g3b,     // [1]
    const float* __restrict__ dscale,  // [1]
    const float* __restrict__ bfg,     // [B*NBC][HID]
    float* __restrict__ uc)            // [B][P_TOTAL]
{
    const int b   = blockIdx.y;
    const int p0  = blockIdx.x * PT;
    const int tid = threadIdx.x;
    const int pl  = tid & (PT-1);     // 0..15
    const int nb  = tid >> 4;         // 0..15

    __shared__ float s_cg[PT][HID+1];   // +1 pad: bank = (pl+k)%32, conflict-free
    __shared__ float s_bcx[NBC];
    __shared__ float s_bcy[NBC];
    __shared__ float s_red[16][PT];

    // coarse-coord projection tile: cg[p][k] = gx*g1w_c0[k] + gy*g1w_c1[k]
    for (int i = tid; i < PT*HID; i += 256) {
        int p_l = i >> 6, k = i & 63;
        int p = p0 + p_l;
        float gx = -1.0f + (2.0f/(WC-1)) * (float)(p & (WC-1));
        float gy = -1.0f + (2.0f/(HC-1)) * (float)(p >> 6);
        s_cg[p_l][k] = gx * g1w[64*HID + k] + gy * g1w[65*HID + k];
    }
    if (tid < NBC) {
        s_bcx[tid] = bi[(b*NBC + tid)*3 + 0];
        s_bcy[tid] = bi[(b*NBC + tid)*3 + 1];
    }
    __syncthreads();

    const int p = p0 + pl;
    const float gx = -1.0f + (2.0f/(WC-1)) * (float)(p & (WC-1));
    const float gy = -1.0f + (2.0f/(HC-1)) * (float)(p >> 6);
    const float as = fabsf(dscale[0]);
    const float g3bias = g3b[0];

    float acc = 0.0f;
    for (int n = nb; n < NBC; n += 16) {
        float dx = s_bcx[n] - gx;
        float dy = s_bcy[n] - gy;
        float dist = sqrtf(dx*dx + dy*dy + 1e-8f);
        float wgt = expf(-as * dist);
        const float* bf_row = bfg + (b*NBC + n)*HID;

        float h2a[32];
        #pragma unroll
        for (int j = 0; j < 32; ++j) h2a[j] = g2b[j];   // uniform -> s_load

        #pragma unroll 4
        for (int k = 0; k < HID; ++k) {
            float h1 = gelu_exact(bf_row[k] + s_cg[pl][k] + dist * g1w[66*HID + k]);
            #pragma unroll
            for (int j = 0; j < 32; ++j) h2a[j] += h1 * g2w[k*32 + j];  // uniform g2w -> s_load
        }

        float raw = g3bias;
        #pragma unroll
        for (int j = 0; j < 32; ++j) raw += gelu_exact(h2a[j]) * g3w[j];
        acc += raw * wgt;
    }

    s_red[nb][pl] = acc;
    __syncthreads();
    if (tid < PT) {
        float s = 0.0f;
        #pragma unroll
        for (int j = 0; j < 16; ++j) s += s_red[j][tid];
        uc[b*P_TOTAL + p0 + tid] = s * (1.0f/NBC);
    }
}

// ---------------------------------------------------------------------------
// Kernel C: bilinear align_corners upsample (B,1,64,64) -> (B,1,256,256)
// ---------------------------------------------------------------------------
__global__ void bg_upsample(const float* __restrict__ uc, float* __restrict__ out) {
    int idx = blockIdx.x * 256 + threadIdx.x;
    if (idx >= B*HOUT*WOUT) return;
    int x = idx & (WOUT-1);
    int y = (idx >> 8) & (HOUT-1);
    int b = idx >> 16;
    float fy = (float)y * ((float)(HC-1)/(float)(HOUT-1));
    float fx = (float)x * ((float)(WC-1)/(float)(WOUT-1));
    int y0 = (int)floorf(fy);
    int x0 = (int)floorf(fx);
    int y1 = min(y0+1, HC-1);
    int x1 = min(x0+1, WC-1);
    float wy = fy - (float)y0;
    float wx = fx - (float)x0;
    const float* u = uc + b*P_TOTAL;
    float v00 = u[y0*WC+x0], v01 = u[y0*WC+x1];
    float v10 = u[y1*WC+x0], v11 = u[y1*WC+x1];
    float top = v00 + (v01 - v00)*wx;
    float bot = v10 + (v11 - v10)*wx;
    out[idx] = top + (bot - top)*wy;
}

extern "C" void kernel_launch(void* const* d_in, const int* in_sizes, int n_in,
                              void* d_out, int out_size, void* d_ws, size_t ws_size,
                              hipStream_t stream) {
    const float* bi  = (const float*)d_in[0];
    // d_in[1] = interior_coords (unused by the reference)
    const float* e1w = (const float*)d_in[2];
    const float* e1b = (const float*)d_in[3];
    const float* e2w = (const float*)d_in[4];
    const float* e2b = (const float*)d_in[5];
    const float* g1w = (const float*)d_in[6];
    const float* g1b = (const float*)d_in[7];
    const float* g2w = (const float*)d_in[8];
    const float* g2b = (const float*)d_in[9];
    const float* g3w = (const float*)d_in[10];
    const float* g3b = (const float*)d_in[11];
    const float* ds  = (const float*)d_in[12];
    float* out = (float*)d_out;

    float* bfg = (float*)d_ws;                 // B*NBC*HID floats
    float* uc  = bfg + B*NBC*HID;              // B*P_TOTAL floats

    bg_encode<<<dim3(B*NBC), dim3(64), 0, stream>>>(bi, e1w, e1b, e2w, e2b, g1w, g1b, bfg);
    dim3 gmain(P_TOTAL/PT, B);
    bg_main<<<gmain, dim3(256), 0, stream>>>(bi, g1w, g2w, g2b, g3w, g3b, ds, bfg, uc);
    bg_upsample<<<dim3((B*HOUT*WOUT)/256), dim3(256), 0, stream>>>(uc, out);
}

// Round 2
// 171.104 us; speedup vs baseline: 1.1672x; 1.1672x over previous
//
#include <hip/hip_runtime.h>
#include <math.h>

#define B 4
#define NBC 128
#define HID 64
#define HC 64
#define WC 64
#define P_TOTAL (HC*WC)
#define HOUT 256
#define WOUT 256
#define PT 8    // coarse points per block in main kernel

// Fast exact-gelu: erf via Abramowitz-Stegun 7.1.26 (|err| <= 1.5e-7),
// hardware v_rcp + v_exp. ~14 VALU ops vs ~45-50 for libm erff.
__device__ __forceinline__ float gelu_fast(float x) {
    float y = fabsf(x) * 0.70710678118654752f;      // |x|/sqrt(2)
    float t = __builtin_amdgcn_rcpf(fmaf(0.3275911f, y, 1.0f));
    float p = fmaf(1.061405429f, t, -1.453152027f);
    p = fmaf(p, t, 1.421413741f);
    p = fmaf(p, t, -0.284496736f);
    p = fmaf(p, t, 0.254829592f);
    p = p * t;
    float e = __expf(-y * y);                        // v_exp_f32
    float er = fmaf(-p, e, 1.0f);                    // erf(|x|/sqrt2)
    float s = copysignf(er, x);                      // sign(x)*erf(|x|/sqrt2)
    return 0.5f * x * (1.0f + s);
}

// ---------------------------------------------------------------------------
// Kernel A: per-(b,n) boundary encoder + fold bfg = bf @ g1w_f + g1b
// ---------------------------------------------------------------------------
__global__ void bg_encode(const float* __restrict__ bi,
                          const float* __restrict__ e1w, const float* __restrict__ e1b,
                          const float* __restrict__ e2w, const float* __restrict__ e2b,
                          const float* __restrict__ g1w, const float* __restrict__ g1b,
                          float* __restrict__ bfg) {
    int bn = blockIdx.x;          // 0..B*NBC-1
    int h  = threadIdx.x;         // 0..63
    __shared__ float t1[HID];
    __shared__ float t2[HID];
    float x = bi[bn*3+0], y = bi[bn*3+1], z = bi[bn*3+2];
    float a = x*e1w[0*HID+h] + y*e1w[1*HID+h] + z*e1w[2*HID+h] + e1b[h];
    t1[h] = gelu_fast(a);
    __syncthreads();
    float s = e2b[h];
    #pragma unroll
    for (int k = 0; k < HID; ++k) s += t1[k]*e2w[k*HID+h];
    t2[h] = gelu_fast(s);
    __syncthreads();
    float o = g1b[h];
    #pragma unroll
    for (int k = 0; k < HID; ++k) o += t2[k]*g1w[k*HID+h];   // g1w_f rows 0..63
    bfg[bn*HID+h] = o;
}

// ---------------------------------------------------------------------------
// Kernel B: main contraction over boundary points.
// Block: 256 threads = 8 p_local x 32 n_lanes. Grid: (P_TOTAL/PT, B).
// ---------------------------------------------------------------------------
__global__ __launch_bounds__(256) void bg_main(
    const float* __restrict__ bi,
    const float* __restrict__ g1w,     // rows 64,65 = g1w_c ; row 66 = g1w_d
    const float* __restrict__ g2w,     // [64][32]
    const float* __restrict__ g2b,     // [32]
    const float* __restrict__ g3w,     // [32]
    const float* __restrict__ g3b,     // [1]
    const float* __restrict__ dscale,  // [1]
    const float* __restrict__ bfg,     // [B*NBC][HID]
    float* __restrict__ uc)            // [B][P_TOTAL]
{
    const int b   = blockIdx.y;
    const int p0  = blockIdx.x * PT;
    const int tid = threadIdx.x;
    const int pl  = tid & (PT-1);     // 0..7
    const int nb  = tid >> 3;         // 0..31

    __shared__ float s_cg[PT][HID+1];   // +1 pad: bank = (pl+k)%32-ish, conflict-free
    __shared__ float s_bcx[NBC];
    __shared__ float s_bcy[NBC];
    __shared__ float s_red[32][PT];

    // coarse-coord projection tile: cg[p][k] = gx*g1w_c0[k] + gy*g1w_c1[k]
    for (int i = tid; i < PT*HID; i += 256) {
        int p_l = i >> 6, k = i & 63;
        int p = p0 + p_l;
        float gx = -1.0f + (2.0f/(WC-1)) * (float)(p & (WC-1));
        float gy = -1.0f + (2.0f/(HC-1)) * (float)(p >> 6);
        s_cg[p_l][k] = gx * g1w[64*HID + k] + gy * g1w[65*HID + k];
    }
    if (tid < NBC) {
        s_bcx[tid] = bi[(b*NBC + tid)*3 + 0];
        s_bcy[tid] = bi[(b*NBC + tid)*3 + 1];
    }
    __syncthreads();

    const int p = p0 + pl;
    const float gx = -1.0f + (2.0f/(WC-1)) * (float)(p & (WC-1));
    const float gy = -1.0f + (2.0f/(HC-1)) * (float)(p >> 6);
    const float as = fabsf(dscale[0]);
    const float g3bias = g3b[0];

    float acc = 0.0f;
    #pragma unroll
    for (int n = nb; n < NBC; n += 32) {
        float dx = s_bcx[n] - gx;
        float dy = s_bcy[n] - gy;
        float dist = sqrtf(dx*dx + dy*dy + 1e-8f);
        float wgt = __expf(-as * dist);
        const float* bf_row = bfg + (b*NBC + n)*HID;

        float h2a[32];
        #pragma unroll
        for (int j = 0; j < 32; ++j) h2a[j] = g2b[j];   // uniform -> s_load

        #pragma unroll 4
        for (int k = 0; k < HID; ++k) {
            float h1 = gelu_fast(bf_row[k] + s_cg[pl][k] + dist * g1w[66*HID + k]);
            #pragma unroll
            for (int j = 0; j < 32; ++j) h2a[j] += h1 * g2w[k*32 + j];  // uniform g2w -> s_load
        }

        float raw = g3bias;
        #pragma unroll
        for (int j = 0; j < 32; ++j) raw += gelu_fast(h2a[j]) * g3w[j];
        acc += raw * wgt;
    }

    s_red[nb][pl] = acc;
    __syncthreads();
    if (tid < PT) {
        float s = 0.0f;
        #pragma unroll
        for (int j = 0; j < 32; ++j) s += s_red[j][tid];
        uc[b*P_TOTAL + p0 + tid] = s * (1.0f/NBC);
    }
}

// ---------------------------------------------------------------------------
// Kernel C: bilinear align_corners upsample (B,1,64,64) -> (B,1,256,256)
// ---------------------------------------------------------------------------
__global__ void bg_upsample(const float* __restrict__ uc, float* __restrict__ out) {
    int idx = blockIdx.x * 256 + threadIdx.x;
    if (idx >= B*HOUT*WOUT) return;
    int x = idx & (WOUT-1);
    int y = (idx >> 8) & (HOUT-1);
    int b = idx >> 16;
    float fy = (float)y * ((float)(HC-1)/(float)(HOUT-1));
    float fx = (float)x * ((float)(WC-1)/(float)(WOUT-1));
    int y0 = (int)floorf(fy);
    int x0 = (int)floorf(fx);
    int y1 = min(y0+1, HC-1);
    int x1 = min(x0+1, WC-1);
    float wy = fy - (float)y0;
    float wx = fx - (float)x0;
    const float* u = uc + b*P_TOTAL;
    float v00 = u[y0*WC+x0], v01 = u[y0*WC+x1];
    float v10 = u[y1*WC+x0], v11 = u[y1*WC+x1];
    float top = v00 + (v01 - v00)*wx;
    float bot = v10 + (v11 - v10)*wx;
    out[idx] = top + (bot - top)*wy;
}

extern "C" void kernel_launch(void* const* d_in, const int* in_sizes, int n_in,
                              void* d_out, int out_size, void* d_ws, size_t ws_size,
                              hipStream_t stream) {
    const float* bi  = (const float*)d_in[0];
    // d_in[1] = interior_coords (unused by the reference)
    const float* e1w = (const float*)d_in[2];
    const float* e1b = (const float*)d_in[3];
    const float* e2w = (const float*)d_in[4];
    const float* e2b = (const float*)d_in[5];
    const float* g1w = (const float*)d_in[6];
    const float* g1b = (const float*)d_in[7];
    const float* g2w = (const float*)d_in[8];
    const float* g2b = (const float*)d_in[9];
    const float* g3w = (const float*)d_in[10];
    const float* g3b = (const float*)d_in[11];
    const float* ds  = (const float*)d_in[12];
    float* out = (float*)d_out;

    float* bfg = (float*)d_ws;                 // B*NBC*HID floats
    float* uc  = bfg + B*NBC*HID;              // B*P_TOTAL floats

    bg_encode<<<dim3(B*NBC), dim3(64), 0, stream>>>(bi, e1w, e1b, e2w, e2b, g1w, g1b, bfg);
    dim3 gmain(P_TOTAL/PT, B);
    bg_main<<<gmain, dim3(256), 0, stream>>>(bi, g1w, g2w, g2b, g3w, g3b, ds, bfg, uc);
    bg_upsample<<<dim3((B*HOUT*WOUT)/256), dim3(256), 0, stream>>>(uc, out);
}

// Round 3
// 122.731 us; speedup vs baseline: 1.6272x; 1.3941x over previous
//
#include <hip/hip_runtime.h>
#include <math.h>

#define B 4
#define NBC 128
#define HID 64
#define HC 64
#define WC 64
#define P_TOTAL (HC*WC)
#define HOUT 256
#define WOUT 256

typedef __attribute__((ext_vector_type(8)))  short bs8;   // 8 bf16 (4 VGPRs) MFMA A/B frag
typedef __attribute__((ext_vector_type(16))) float fx16;  // 32x32 MFMA C/D frag

// Fast exact-gelu: erf via Abramowitz-Stegun 7.1.26 (|err| <= 1.5e-7).
__device__ __forceinline__ float gelu_fast(float x) {
    float y = fabsf(x) * 0.70710678118654752f;
    float t = __builtin_amdgcn_rcpf(fmaf(0.3275911f, y, 1.0f));
    float p = fmaf(1.061405429f, t, -1.453152027f);
    p = fmaf(p, t, 1.421413741f);
    p = fmaf(p, t, -0.284496736f);
    p = fmaf(p, t, 0.254829592f);
    p = p * t;
    float e = __expf(-y * y);
    float er = fmaf(-p, e, 1.0f);
    float s = copysignf(er, x);
    return 0.5f * x * (1.0f + s);
}

// fp32 -> bf16 bits, round-to-nearest-even
__device__ __forceinline__ short f2bf(float f) {
    unsigned u = __float_as_uint(f);
    unsigned r = (u + 0x7FFFu + ((u >> 16) & 1u)) >> 16;
    return (short)r;
}
__device__ __forceinline__ float bf2f(short h) {
    return __uint_as_float(((unsigned)(unsigned short)h) << 16);
}

// ---------------------------------------------------------------------------
// Kernel A: per-(b,n) boundary encoder + fold bfg = bf @ g1w_f + g1b
// ---------------------------------------------------------------------------
__global__ void bg_encode(const float* __restrict__ bi,
                          const float* __restrict__ e1w, const float* __restrict__ e1b,
                          const float* __restrict__ e2w, const float* __restrict__ e2b,
                          const float* __restrict__ g1w, const float* __restrict__ g1b,
                          float* __restrict__ bfg) {
    int bn = blockIdx.x;
    int h  = threadIdx.x;
    __shared__ float t1[HID];
    __shared__ float t2[HID];
    float x = bi[bn*3+0], y = bi[bn*3+1], z = bi[bn*3+2];
    float a = x*e1w[0*HID+h] + y*e1w[1*HID+h] + z*e1w[2*HID+h] + e1b[h];
    t1[h] = gelu_fast(a);
    __syncthreads();
    float s = e2b[h];
    #pragma unroll
    for (int k = 0; k < HID; ++k) s += t1[k]*e2w[k*HID+h];
    t2[h] = gelu_fast(s);
    __syncthreads();
    float o = g1b[h];
    #pragma unroll
    for (int k = 0; k < HID; ++k) o += t2[k]*g1w[k*HID+h];
    bfg[bn*HID+h] = o;
}

// ---------------------------------------------------------------------------
// Kernel B: main contraction. Block = 256 thr (4 waves), grid (128 p-tiles, B).
// Each wave: same 32-p tile, its own 32 n's. h1 built per-lane in registers,
// h1@g2w on MFMA (g2w split hi+lo bf16 for accuracy), gelu+dot on VALU.
// MFMA 32x32x16 layouts: A row=lane&31, k=16m+8*(lane>>5)+e (A,B use the SAME
// k function so any within-k permutation error cancels); C/D row/col per m101.
// ---------------------------------------------------------------------------
__global__ __launch_bounds__(256, 2) void bg_main(
    const float* __restrict__ bi,
    const float* __restrict__ g1w,     // rows 64,65 = g1w_c ; row 66 = g1w_d
    const float* __restrict__ g2w,     // [64][32]
    const float* __restrict__ g2b,     // [32]
    const float* __restrict__ g3w,     // [32]
    const float* __restrict__ g3b,     // [1]
    const float* __restrict__ dscale,  // [1]
    const float* __restrict__ bfg,     // [B*NBC][HID]
    float* __restrict__ uc)            // [B][P_TOTAL]
{
    const int b    = blockIdx.y;
    const int p0   = blockIdx.x * 32;
    const int tid  = threadIdx.x;
    const int lane = tid & 63;
    const int wid  = tid >> 6;        // 0..3, n-chunk
    const int row  = lane & 31;       // A row / C col
    const int half = lane >> 5;       // k sub-chunk

    __shared__ float s_bfg[NBC][HID];   // 32 KB
    __shared__ float s_bcx[NBC];
    __shared__ float s_bcy[NBC];
    __shared__ float s_red[4][32];

    {   // stage bfg for this b (coalesced float4)
        const float4* src = (const float4*)(bfg + b*NBC*HID);
        float4* dst = (float4*)(&s_bfg[0][0]);
        #pragma unroll
        for (int i = 0; i < 8; ++i)           // 2048 float4 / 256 thr
            dst[tid + i*256] = src[tid + i*256];
    }
    if (tid < NBC) {
        s_bcx[tid] = bi[(b*NBC + tid)*3 + 0];
        s_bcy[tid] = bi[(b*NBC + tid)*3 + 1];
    }
    __syncthreads();

    const int p = p0 + row;
    const float gx = -1.0f + (2.0f/(WC-1)) * (float)(p & (WC-1));
    const float gy = -1.0f + (2.0f/(HC-1)) * (float)(p >> 6);

    // per-lane resident constants: cg, g1d for this lane's 32 (row,k) slots;
    // g2w B-fragments split hi/lo
    float cgv[4][8], g1dv[4][8];
    bs8 whi[4], wlo[4];
    #pragma unroll
    for (int m = 0; m < 4; ++m) {
        #pragma unroll
        for (int e = 0; e < 8; ++e) {
            int k = m*16 + half*8 + e;
            cgv[m][e]  = gx * g1w[64*HID + k] + gy * g1w[65*HID + k];
            g1dv[m][e] = g1w[66*HID + k];
            float w = g2w[k*32 + row];
            short hi = f2bf(w);
            whi[m][e] = hi;
            wlo[m][e] = f2bf(w - bf2f(hi));
        }
    }
    const float g2b_col = g2b[row];
    const float g3w_col = g3w[row];
    const float as = fabsf(dscale[0]);
    const float g3bias = g3b[0];

    fx16 outacc;
    #pragma unroll
    for (int r = 0; r < 16; ++r) outacc[r] = 0.0f;
    float wsum = 0.0f;

    for (int ni = 0; ni < 32; ++ni) {
        const int n = wid*32 + ni;
        float dx = s_bcx[n] - gx;
        float dy = s_bcy[n] - gy;
        float dist = sqrtf(dx*dx + dy*dy + 1e-8f);
        float wgt = __expf(-as * dist);
        wsum += wgt;

        fx16 acc0, acc1;
        #pragma unroll
        for (int r = 0; r < 16; ++r) { acc0[r] = g2b_col; acc1[r] = 0.0f; }

        #pragma unroll
        for (int m = 0; m < 4; ++m) {
            bs8 af;
            #pragma unroll
            for (int e = 0; e < 8; ++e) {
                float u = s_bfg[n][m*16 + half*8 + e]
                        + fmaf(dist, g1dv[m][e], cgv[m][e]);
                af[e] = f2bf(gelu_fast(u));
            }
            if (m < 2) {
                acc0 = __builtin_amdgcn_mfma_f32_32x32x16_bf16(af, whi[m], acc0, 0, 0, 0);
                acc0 = __builtin_amdgcn_mfma_f32_32x32x16_bf16(af, wlo[m], acc0, 0, 0, 0);
            } else {
                acc1 = __builtin_amdgcn_mfma_f32_32x32x16_bf16(af, whi[m], acc1, 0, 0, 0);
                acc1 = __builtin_amdgcn_mfma_f32_32x32x16_bf16(af, wlo[m], acc1, 0, 0, 0);
            }
        }

        // epilogue: gelu(h2) * wgt[row-of-this-C-element], accumulate over n
        #pragma unroll
        for (int r = 0; r < 16; ++r) {
            float h2 = acc0[r] + acc1[r];
            float g = gelu_fast(h2);
            int crow = (r & 3) + 8*(r >> 2) + 4*half;
            float wv = __shfl(wgt, crow, 64);
            outacc[r] += g * wv;
        }
    }

    // fold g3w (per-col) then reduce across the 32 columns
    float d[16];
    #pragma unroll
    for (int r = 0; r < 16; ++r) d[r] = outacc[r] * g3w_col;
    #pragma unroll
    for (int off = 16; off >= 1; off >>= 1) {
        #pragma unroll
        for (int r = 0; r < 16; ++r) d[r] += __shfl_xor(d[r], off, 32);
    }
    float Wr[16];
    #pragma unroll
    for (int r = 0; r < 16; ++r)
        Wr[r] = __shfl(wsum, (r & 3) + 8*(r >> 2) + 4*half, 64);

    if ((lane & 31) == 0) {
        #pragma unroll
        for (int r = 0; r < 16; ++r)
            s_red[wid][(r & 3) + 8*(r >> 2) + 4*half] = d[r] + g3bias * Wr[r];
    }
    __syncthreads();
    if (tid < 32) {
        float s = s_red[0][tid] + s_red[1][tid] + s_red[2][tid] + s_red[3][tid];
        uc[b*P_TOTAL + p0 + tid] = s * (1.0f/NBC);
    }
}

// ---------------------------------------------------------------------------
// Kernel C: bilinear align_corners upsample (B,1,64,64) -> (B,1,256,256)
// ---------------------------------------------------------------------------
__global__ void bg_upsample(const float* __restrict__ uc, float* __restrict__ out) {
    int idx = blockIdx.x * 256 + threadIdx.x;
    if (idx >= B*HOUT*WOUT) return;
    int x = idx & (WOUT-1);
    int y = (idx >> 8) & (HOUT-1);
    int b = idx >> 16;
    float fy = (float)y * ((float)(HC-1)/(float)(HOUT-1));
    float fx = (float)x * ((float)(WC-1)/(float)(WOUT-1));
    int y0 = (int)floorf(fy);
    int x0 = (int)floorf(fx);
    int y1 = min(y0+1, HC-1);
    int x1 = min(x0+1, WC-1);
    float wy = fy - (float)y0;
    float wx = fx - (float)x0;
    const float* u = uc + b*P_TOTAL;
    float v00 = u[y0*WC+x0], v01 = u[y0*WC+x1];
    float v10 = u[y1*WC+x0], v11 = u[y1*WC+x1];
    float top = v00 + (v01 - v00)*wx;
    float bot = v10 + (v11 - v10)*wx;
    out[idx] = top + (bot - top)*wy;
}

extern "C" void kernel_launch(void* const* d_in, const int* in_sizes, int n_in,
                              void* d_out, int out_size, void* d_ws, size_t ws_size,
                              hipStream_t stream) {
    const float* bi  = (const float*)d_in[0];
    const float* e1w = (const float*)d_in[2];
    const float* e1b = (const float*)d_in[3];
    const float* e2w = (const float*)d_in[4];
    const float* e2b = (const float*)d_in[5];
    const float* g1w = (const float*)d_in[6];
    const float* g1b = (const float*)d_in[7];
    const float* g2w = (const float*)d_in[8];
    const float* g2b = (const float*)d_in[9];
    const float* g3w = (const float*)d_in[10];
    const float* g3b = (const float*)d_in[11];
    const float* ds  = (const float*)d_in[12];
    float* out = (float*)d_out;

    float* bfg = (float*)d_ws;                 // B*NBC*HID floats
    float* uc  = bfg + B*NBC*HID;              // B*P_TOTAL floats

    bg_encode<<<dim3(B*NBC), dim3(64), 0, stream>>>(bi, e1w, e1b, e2w, e2b, g1w, g1b, bfg);
    bg_main<<<dim3(P_TOTAL/32, B), dim3(256), 0, stream>>>(bi, g1w, g2w, g2b, g3w, g3b, ds, bfg, uc);
    bg_upsample<<<dim3((B*HOUT*WOUT)/256), dim3(256), 0, stream>>>(uc, out);
}